// Round 1
// baseline (197.195 us; speedup 1.0000x reference)
//
#include <hip/hip_runtime.h>
#include <hip/hip_bf16.h>

#define IMG 256
#define NG 1024
constexpr float PIX  = 1.0f / 256.0f;
constexpr float TTH  = 0.0001f;
constexpr float ACLIP = 0.99f;

// ws layout: float params[NG][12] = {mx,my,i00,ioff,i11,alpha,cr,cg,cb,pad,pad,pad}

__global__ __launch_bounds__(1024)
void gs_prep(const float* __restrict__ mean, const float* __restrict__ cov,
             const float* __restrict__ color, const float* __restrict__ alpha,
             const float* __restrict__ depth, float* __restrict__ params)
{
    __shared__ float sdepth[NG];
    const int t = threadIdx.x;          // one block of 1024 threads
    sdepth[t] = depth[t];
    __syncthreads();
    const float d = sdepth[t];
    int rank = 0;
    #pragma unroll 8
    for (int j = 0; j < NG; ++j) {
        const float dj = sdepth[j];
        rank += (dj < d) || (dj == d && j < t);   // stable ascending rank
    }
    const float a  = cov[t * 4 + 0];
    const float b  = cov[t * 4 + 1];
    const float c  = cov[t * 4 + 2];
    const float dd = cov[t * 4 + 3];
    const float det    = a * dd - b * c;
    const float inv00  = dd / det;
    const float inv11  = a / det;
    const float invoff = -(b + c) / det;

    float* o = params + rank * 12;
    o[0] = mean[t * 2 + 0];
    o[1] = mean[t * 2 + 1];
    o[2] = inv00;
    o[3] = invoff;
    o[4] = inv11;
    o[5] = alpha[t];
    o[6] = color[t * 3 + 0];
    o[7] = color[t * 3 + 1];
    o[8] = color[t * 3 + 2];
    o[9] = 0.0f; o[10] = 0.0f; o[11] = 0.0f;
}

__global__ __launch_bounds__(256)
void gs_render(const float* __restrict__ params, const float* __restrict__ bg,
               const float* __restrict__ topleft, float* __restrict__ out)
{
    __shared__ float4 sg[NG * 3];       // 48 KiB
    const int tid = threadIdx.x;

    const float4* p4 = (const float4*)params;
    #pragma unroll
    for (int i = 0; i < NG * 3 / 256; ++i)
        sg[tid + i * 256] = p4[tid + i * 256];
    __syncthreads();

    const int p   = blockIdx.x * 256 + tid;
    const int row = p >> 8;
    const int col = p & 255;
    const float px = ((float)col + 0.5f) * PIX - topleft[0];
    const float py = ((float)row + 0.5f) * PIX - topleft[1];

    float T = 1.0f, r = 0.0f, g = 0.0f, b = 0.0f;

    for (int i = 0; i < NG; ++i) {
        if ((i & 63) == 0) {
            if (__all(T <= TTH)) break;      // whole wave saturated
        }
        const float4 q0 = sg[i * 3 + 0];     // mx,my,i00,ioff
        const float4 q1 = sg[i * 3 + 1];     // i11,alpha,cr,cg
        const float4 q2 = sg[i * 3 + 2];     // cb,-,-,-

        const float dx = px - q0.x;
        const float dy = py - q0.y;
        const float quad = dx * (q0.z * dx + q0.w * dy) + q1.x * dy * dy;
        const float e = __expf(-0.5f * quad);
        const float a = fminf(q1.y * e, ACLIP);

        const bool act = T > TTH;
        const float w = act ? a * T : 0.0f;
        r = fmaf(w, q1.z, r);
        g = fmaf(w, q1.w, g);
        b = fmaf(w, q2.x, b);
        T = act ? T * (1.0f - a) : T;
    }

    const float* bgp = bg + p * 3;
    float* op = out + p * 3;
    op[0] = r + T * bgp[0];
    op[1] = g + T * bgp[1];
    op[2] = b + T * bgp[2];
}

extern "C" void kernel_launch(void* const* d_in, const int* in_sizes, int n_in,
                              void* d_out, int out_size, void* d_ws, size_t ws_size,
                              hipStream_t stream) {
    const float* mean    = (const float*)d_in[0];
    const float* cov     = (const float*)d_in[1];
    const float* color   = (const float*)d_in[2];
    const float* alpha   = (const float*)d_in[3];
    const float* depth   = (const float*)d_in[4];
    const float* bg      = (const float*)d_in[5];
    const float* topleft = (const float*)d_in[6];
    float* out    = (float*)d_out;
    float* params = (float*)d_ws;       // NG*12 floats = 48 KiB

    gs_prep<<<1, 1024, 0, stream>>>(mean, cov, color, alpha, depth, params);
    gs_render<<<IMG * IMG / 256, 256, 0, stream>>>(params, bg, topleft, out);
}

// Round 2
// 108.049 us; speedup vs baseline: 1.8251x; 1.8251x over previous
//
#include <hip/hip_runtime.h>
#include <hip/hip_bf16.h>

#define IMG 256
#define NG 1024
constexpr float PIX   = 1.0f / 256.0f;
constexpr float TTH   = 0.0001f;
constexpr float ACLIP = 0.99f;

// ws layout: float params[NG][12] = {mx,my,i00,ioff,i11,alpha,cr,cg,cb,rx,ry,pad}
// (rx,ry = conservative bbox half-extents for a_eff >= 1e-6 cutoff)

__global__ __launch_bounds__(256)
void gs_prep(const float* __restrict__ mean, const float* __restrict__ cov,
             const float* __restrict__ color, const float* __restrict__ alpha,
             const float* __restrict__ depth, float* __restrict__ params)
{
    __shared__ float sdepth[NG];
    const int tid = threadIdx.x;
    const int t   = blockIdx.x * 256 + tid;       // gaussian id (4 blocks x 256)

    for (int i = tid; i < NG; i += 256) sdepth[i] = depth[i];
    __syncthreads();

    const float d = sdepth[t];
    int rank = 0;
    const float4* s4 = (const float4*)sdepth;
    #pragma unroll 4
    for (int j4 = 0; j4 < NG / 4; ++j4) {
        const float4 dj = s4[j4];                 // broadcast read
        const int j = j4 * 4;
        rank += (dj.x < d) || (dj.x == d && (j + 0) < t);
        rank += (dj.y < d) || (dj.y == d && (j + 1) < t);
        rank += (dj.z < d) || (dj.z == d && (j + 2) < t);
        rank += (dj.w < d) || (dj.w == d && (j + 3) < t);
    }

    const float a  = cov[t * 4 + 0];
    const float b  = cov[t * 4 + 1];
    const float c  = cov[t * 4 + 2];
    const float dd = cov[t * 4 + 3];
    const float det    = a * dd - b * c;
    const float inv00  = dd / det;
    const float inv11  = a / det;
    const float invoff = -(b + c) / det;

    const float al = alpha[t];
    // cutoff: a_eff = al*exp(-q/2) < 1e-6  ->  q > 2*ln(al*1e6)
    float qcut = 2.0f * __logf(al * 1.0e6f + 1.0e-30f);
    qcut = fminf(fmaxf(qcut, 0.0f), 28.0f);
    const float rx = sqrtf(qcut * fmaxf(a,  0.0f));   // ellipse x-extent = sqrt(q*Sxx)
    const float ry = sqrtf(qcut * fmaxf(dd, 0.0f));

    float* o = params + rank * 12;
    o[0] = mean[t * 2 + 0];
    o[1] = mean[t * 2 + 1];
    o[2] = inv00;
    o[3] = invoff;
    o[4] = inv11;
    o[5] = al;
    o[6] = color[t * 3 + 0];
    o[7] = color[t * 3 + 1];
    o[8] = color[t * 3 + 2];
    o[9] = rx; o[10] = ry; o[11] = 0.0f;
}

__global__ __launch_bounds__(256)
void gs_render(const float* __restrict__ params, const float* __restrict__ bg,
               const float* __restrict__ topleft, float* __restrict__ out)
{
    __shared__ float4 sg[NG * 3];                 // 48 KiB
    const int tid = threadIdx.x;

    const float4* p4 = (const float4*)params;
    #pragma unroll
    for (int i = 0; i < 12; ++i)
        sg[tid + i * 256] = p4[tid + i * 256];
    __syncthreads();

    const int tile = blockIdx.x;                  // 256 tiles of 16x16 px
    const int tx = (tile & 15) * 16;
    const int ty = (tile >> 4) * 16;
    const int col = tx + (tid & 15);
    const int row = ty + (tid >> 4);
    const float tl0 = topleft[0], tl1 = topleft[1];
    const float px = ((float)col + 0.5f) * PIX - tl0;
    const float py = ((float)row + 0.5f) * PIX - tl1;

    // tile bbox (pixel centers) in gaussian space
    const float cxt = ((float)tx + 8.0f) * PIX - tl0;
    const float cyt = ((float)ty + 8.0f) * PIX - tl1;
    const float hx  = 7.5f * PIX;
    const float hy  = 7.5f * PIX;

    float T = 1.0f, r = 0.0f, g = 0.0f, b = 0.0f;
    const int lane = tid & 63;

    for (int c = 0; c < NG / 64; ++c) {
        if (__all(T <= TTH)) break;               // whole wave saturated

        // lane tests gaussian c*64+lane against the tile bbox
        const int gi = c * 64 + lane;
        const float4 t0 = sg[gi * 3 + 0];         // mx,my,i00,ioff
        const float4 t2 = sg[gi * 3 + 2];         // cb,rx,ry,-
        const bool hit = (fabsf(t0.x - cxt) <= t2.y + hx) &&
                         (fabsf(t0.y - cyt) <= t2.z + hy);
        unsigned long long mask = __ballot(hit);  // wave-uniform, bit j = gaussian c*64+j

        while (mask) {
            const int j = __ffsll(mask) - 1;
            mask &= mask - 1;
            const int gg = c * 64 + j;            // uniform -> broadcast LDS reads
            const float4 a0 = sg[gg * 3 + 0];
            const float4 a1 = sg[gg * 3 + 1];
            const float cb = sg[gg * 3 + 2].x;

            const float dx = px - a0.x;
            const float dy = py - a0.y;
            const float quad = dx * (a0.z * dx + a0.w * dy) + a1.x * dy * dy;
            const float e = __expf(-0.5f * quad);
            const float aeff = fminf(a1.y * e, ACLIP);

            const bool act = T > TTH;
            const float w = act ? aeff * T : 0.0f;
            r = fmaf(w, a1.z, r);
            g = fmaf(w, a1.w, g);
            b = fmaf(w, cb, b);
            T = act ? T * (1.0f - aeff) : T;
        }
    }

    const int p = row * 256 + col;
    const float* bgp = bg + p * 3;
    float* op = out + p * 3;
    op[0] = r + T * bgp[0];
    op[1] = g + T * bgp[1];
    op[2] = b + T * bgp[2];
}

extern "C" void kernel_launch(void* const* d_in, const int* in_sizes, int n_in,
                              void* d_out, int out_size, void* d_ws, size_t ws_size,
                              hipStream_t stream) {
    const float* mean    = (const float*)d_in[0];
    const float* cov     = (const float*)d_in[1];
    const float* color   = (const float*)d_in[2];
    const float* alpha   = (const float*)d_in[3];
    const float* depth   = (const float*)d_in[4];
    const float* bg      = (const float*)d_in[5];
    const float* topleft = (const float*)d_in[6];
    float* out    = (float*)d_out;
    float* params = (float*)d_ws;                 // NG*12 floats = 48 KiB

    gs_prep<<<4, 256, 0, stream>>>(mean, cov, color, alpha, depth, params);
    gs_render<<<IMG * IMG / 256, 256, 0, stream>>>(params, bg, topleft, out);
}